// Round 5
// baseline (136.791 us; speedup 1.0000x reference)
//
#include <hip/hip_runtime.h>

// HardPartPyramidPooling: x(16,256,32,16,11) fp32, labels(16,32,176) int,
// out(16,256,32,16) fp32.  out[n][c][s][p] = sum/cnt + max (0 if cnt==0),
// max floored at NEG_FILL=-100 (reference init).
//
// R10: SINGLE-WAVE BLOCKS (sync-free). R7/R8/R9 nulls showed the ~25us
// kernel slice is insensitive to barrier drains, DRAM alignment, and
// gather instruction count. Shared trait of all prior versions: 4-wave
// blocks with barrier-phased execution -> bursty per-CU load issue (all
// resident blocks issue loads in lockstep windows, then long compute
// tails). R10 removes inter-wave sync entirely:
//  - block = 1 wave (64 threads) covering (n, even s-pair, 2 channels);
//    grid = 256 nsp x 128 = 32768 independent waves, ~24-32/CU, each
//    scheduled independently -> load issue naturally interleaved.
//  - NO s_barrier anywhere; wave-internal ordering via lgkmcnt(0) fences
//    (asm volatile, memory clobber = compiler fence + HW wait).
//  - x segments: 2 per block, 1408 B, 128-B aligned (as R8/R9).
//  - rank-sorted tile kept from R9: bucket -> 32-lane prefix scan ->
//    posmap -> scatter-store -> CONTIGUOUS b128 gather.
//  - PITCH=180: rows 16-B aligned, bank-spread. LDS ~3.5 KB/block.

constexpr int C   = 256;
constexpr int S   = 32;
constexpr int HW  = 176;        // 16*11
constexpr int P   = 16;
constexpr int ROW = S * HW;     // 5632 floats per (n,c)
constexpr int GC  = 2;          // channels per block
constexpr int NS2 = 2;          // s values per block (even base)
constexpr int PITCH = 180;      // floats; %4==0 (b128 align), /4 odd (bank spread)
constexpr float NEG_FILL = -100.0f;

__device__ __forceinline__ void fence_lds() {
    // wave-internal LDS ordering: compiler fence + wait. No s_barrier
    // (single wave per block).
    asm volatile("s_waitcnt lgkmcnt(0)" ::: "memory");
}

__global__ __launch_bounds__(64) void hpp_kernel(
    const float* __restrict__ x,
    const int*   __restrict__ labels,
    float*       __restrict__ out)
{
    __shared__ float tile[GC * NS2 * PITCH];                 // 4*180*4 = 2880 B
    __shared__ __align__(4) unsigned char posmap[NS2][HW];   // 352 B
    __shared__ int cnt[NS2 * P];                             // 128 B
    __shared__ int base[NS2 * P];                            // 128 B

    const int tid = threadIdx.x;                 // 0..63
    const int blk = blockIdx.x;                  // nsp*128 + cg2
    const int cg2 = blk & 127;
    const int nsp = blk >> 7;
    const int n   = nsp >> 4, sp = nsp & 15;
    const int s   = sp * 2;                      // even
    const int c0  = cg2 * 2;

    // ---- labels FIRST: 352 int32 = 88 int4; lanes 0..63 + lanes 0..23 ----
    const int* ln = labels + (size_t)(n * S + s) * HW;       // 16-B aligned
    int4 L0 = ((const int4*)ln)[tid];
    int4 L1 = make_int4(0, 0, 0, 0);
    const bool hasL1 = (tid < 24);
    if (hasL1) L1 = ((const int4*)ln)[tid + 64];

    // ---- x loads: 176 float4 = 2 channels x 88 (1408 B each, aligned) ----
    const float* xb = x + (size_t)(n * C + c0) * ROW + s * HW;
    // f0 = tid        -> r=0, j=tid
    // f1 = tid+64     -> tid<24: r=0,j=tid+64 ; else r=1,j=tid-24
    // f2 = tid+128    -> r=1, j=tid+40, active tid<48
    const int j0 = tid;
    const int r1 = (tid < 24) ? 0 : 1;
    const int j1 = (tid < 24) ? tid + 64 : tid - 24;
    const int j2 = tid + 40;
    const bool has2 = (tid < 48);
    float4 v0 = *(const float4*)(xb + (size_t)0 * ROW + j0 * 4);
    float4 v1 = *(const float4*)(xb + (size_t)r1 * ROW + j1 * 4);
    float4 v2 = make_float4(0.f, 0.f, 0.f, 0.f);
    if (has2) v2 = *(const float4*)(xb + (size_t)1 * ROW + j2 * 4);

    // ---- bucket both rows (hides under x vmcnt) --------------------------
    if (tid < NS2 * P) cnt[tid] = 0;
    fence_lds();
    // L0: positions 4*tid..4*tid+3.  tid<44 -> row 0 (hw=pos);
    //     tid>=44 -> row 1 (hw=pos-176).  176 = 4*44: no straddle.
    const int row0 = (tid >= 44);
    int a0, a1, a2, a3;                          // ranks
    {
        int* c = &cnt[row0 * P];
        a0 = atomicAdd(&c[L0.x], 1);
        a1 = atomicAdd(&c[L0.y], 1);
        a2 = atomicAdd(&c[L0.z], 1);
        a3 = atomicAdd(&c[L0.w], 1);
    }
    // L1 (lanes 0..23): positions 256+4*tid -> row 1, hw = 80+4*tid.
    int b0 = 0, b1 = 0, b2 = 0, b3 = 0;
    if (hasL1) {
        int* c = &cnt[P];
        b0 = atomicAdd(&c[L1.x], 1);
        b1 = atomicAdd(&c[L1.y], 1);
        b2 = atomicAdd(&c[L1.z], 1);
        b3 = atomicAdd(&c[L1.w], 1);
    }
    fence_lds();
    // prefix scan within each 16-part set (lanes 0..31, <=15 reads)
    if (tid < NS2 * P) {
        int acc = 0;
        const int g0 = tid & ~(P - 1);
        for (int q = g0; q < tid; ++q) acc += cnt[q];
        base[tid] = acc;
    }
    fence_lds();
    {
        const int hw0 = (tid * 4) - row0 * 176;  // 0..172 step4 / 0..76 step4
        const int* bs = &base[row0 * P];
        posmap[row0][hw0    ] = (unsigned char)(bs[L0.x] + a0);
        posmap[row0][hw0 + 1] = (unsigned char)(bs[L0.y] + a1);
        posmap[row0][hw0 + 2] = (unsigned char)(bs[L0.z] + a2);
        posmap[row0][hw0 + 3] = (unsigned char)(bs[L0.w] + a3);
        if (hasL1) {
            const int hw1 = 80 + tid * 4;
            const int* b1s = &base[P];
            posmap[1][hw1    ] = (unsigned char)(b1s[L1.x] + b0);
            posmap[1][hw1 + 1] = (unsigned char)(b1s[L1.y] + b1);
            posmap[1][hw1 + 2] = (unsigned char)(b1s[L1.z] + b2);
            posmap[1][hw1 + 3] = (unsigned char)(b1s[L1.w] + b3);
        }
    }
    fence_lds();

    // ---- scatter-store tile into sorted order ----------------------------
    // float4 (r=channel, j) covers floats 4j..4j+3: s_row = (j>=44),
    // hw = 4j - s_row*176; tile row rt = r*2 + s_row.
    {
        const int s20 = (j0 >= 44), h0 = j0 * 4 - s20 * 176;
        unsigned pm0 = *(const unsigned*)&posmap[s20][h0];
        float* t0 = &tile[(0 * 2 + s20) * PITCH];
        t0[pm0 & 0xFF] = v0.x; t0[(pm0 >> 8) & 0xFF] = v0.y;
        t0[(pm0 >> 16) & 0xFF] = v0.z; t0[pm0 >> 24] = v0.w;

        const int s21 = (j1 >= 44), h1 = j1 * 4 - s21 * 176;
        unsigned pm1 = *(const unsigned*)&posmap[s21][h1];
        float* t1 = &tile[(r1 * 2 + s21) * PITCH];
        t1[pm1 & 0xFF] = v1.x; t1[(pm1 >> 8) & 0xFF] = v1.y;
        t1[(pm1 >> 16) & 0xFF] = v1.z; t1[pm1 >> 24] = v1.w;

        if (has2) {
            const int s22 = (j2 >= 44), h2 = j2 * 4 - s22 * 176;
            unsigned pm2 = *(const unsigned*)&posmap[s22][h2];
            float* t2 = &tile[(1 * 2 + s22) * PITCH];
            t2[pm2 & 0xFF] = v2.x; t2[(pm2 >> 8) & 0xFF] = v2.y;
            t2[(pm2 >> 16) & 0xFF] = v2.z; t2[pm2 >> 24] = v2.w;
        }
    }
    fence_lds();

    // ---- contiguous gather: p = tid>>2; low2: c' = low2>>1, s' = low2&1 --
    const int p   = tid >> 2;
    const int lo  = tid & 3;
    const int cp  = lo >> 1;
    const int sp2 = lo & 1;
    const int idx = sp2 * P + p;
    const int k   = cnt[idx];
    int off       = base[idx];
    const float* tc = &tile[(cp * 2 + sp2) * PITCH];

    float s0 = 0.f, s1 = 0.f, m0 = NEG_FILL, m1 = NEG_FILL;
    int rem = k;
    int h = (4 - (off & 3)) & 3; if (h > rem) h = rem;
    if (h > 0) { float a = tc[off];     s0 += a; m0 = fmaxf(m0, a); }
    if (h > 1) { float a = tc[off + 1]; s1 += a; m1 = fmaxf(m1, a); }
    if (h > 2) { float a = tc[off + 2]; s0 += a; m0 = fmaxf(m0, a); }
    off += h; rem -= h;
    int n4 = rem >> 2;
    for (int i = 0; i < n4; ++i) {
        float4 q = *(const float4*)&tc[off];
        s0 += q.x; m0 = fmaxf(m0, q.x);
        s1 += q.y; m1 = fmaxf(m1, q.y);
        s0 += q.z; m0 = fmaxf(m0, q.z);
        s1 += q.w; m1 = fmaxf(m1, q.w);
        off += 4;
    }
    rem &= 3;
    if (rem > 0) { float a = tc[off];     s0 += a; m0 = fmaxf(m0, a); }
    if (rem > 1) { float a = tc[off + 1]; s1 += a; m1 = fmaxf(m1, a); }
    if (rem > 2) { float a = tc[off + 2]; s0 += a; m0 = fmaxf(m0, a); }

    float res = (k > 0) ? (s0 + s1) / (float)k + fmaxf(m0, m1) : 0.f;
    out[((size_t)(n * C + c0 + cp) * S + (s + sp2)) * P + p] = res;
}

extern "C" void kernel_launch(void* const* d_in, const int* in_sizes, int n_in,
                              void* d_out, int out_size, void* d_ws, size_t ws_size,
                              hipStream_t stream) {
    const float* x      = (const float*)d_in[0];
    const int*   labels = (const int*)d_in[1];
    float*       out    = (float*)d_out;

    const int ns_total = in_sizes[1] / HW;             // 512
    const int nblk     = (ns_total / NS2) * (C / GC);  // 256 * 128 = 32768
    hpp_kernel<<<nblk, 64, 0, stream>>>(x, labels, out);
}